// Round 19
// baseline (437.248 us; speedup 1.0000x reference)
//
#include <hip/hip_runtime.h>

typedef unsigned int u32;
typedef unsigned short u16;
typedef unsigned long long u64;

#define CH_ 128

__device__ __forceinline__ u32 f2ord(float f){
  u32 u = __float_as_uint(f);
  return ((int)u < 0) ? ~u : (u | 0x80000000u);
}
__device__ __forceinline__ float ord2f(u32 u){
  return (u & 0x80000000u) ? __uint_as_float(u & 0x7FFFFFFFu) : __uint_as_float(~u);
}
__device__ __forceinline__ u32 ldu32(const u32* p){
  return __hip_atomic_load(p, __ATOMIC_RELAXED, __HIP_MEMORY_SCOPE_AGENT);
}
__device__ __forceinline__ void stu32(u32* p, u32 v){
  __hip_atomic_store(p, v, __ATOMIC_RELAXED, __HIP_MEMORY_SCOPE_AGENT);
}

// ---------------- init ----------------
// ucap > 0: bucket mode -> offarr[v] = v*ucap (no deg scan needed)
__global__ void k_init(u32* hdr, u32* mxbits, double* den, u64* sw,
                       int* craw, int* medge, u32* deg, u32* acur,
                       u32* wpos, u32* offarr, u32 ucap, int N, int E){
  int i0 = blockIdx.x*blockDim.x + threadIdx.x;
  int nt = gridDim.x*blockDim.x;
  for (int v = i0; v < N; v += nt){
    mxbits[v]=0u; den[v]=0.0; sw[v]=0ull; craw[v]=v; medge[v]=-1;
    deg[v]=0u; acur[v]=0u; wpos[v]=0u;
    if (ucap) offarr[v] = (u32)v * ucap;
  }
  if (i0 == 0){
    for (int i = 0; i < 64; i++) hdr[i] = 0u;
    hdr[6] = (u32)N;
    offarr[N] = ucap ? (u32)N*ucap : (u32)(2*E);
  }
}

// ---------------- per-node dot products: s=x.w1, t=x.w2 ----------------
__global__ void k_dots(const float* __restrict__ x, const float* __restrict__ lw,
                       float* __restrict__ s, float* __restrict__ t, int N){
  int wid = threadIdx.x >> 6, lane = threadIdx.x & 63;
  int node = blockIdx.x*4 + wid;
  if (node >= N) return;
  const float* xr = x + (size_t)node*CH_;
  float xa = xr[lane], xb = xr[64+lane];
  float sv = xa*lw[lane]      + xb*lw[64+lane];
  float tv = xa*lw[128+lane]  + xb*lw[192+lane];
  #pragma unroll
  for (int m = 1; m < 64; m <<= 1){ sv += __shfl_xor(sv, m); tv += __shfl_xor(tv, m); }
  if (lane == 0){ s[node]=sv; t[node]=tv; }
}

// ---------------- raw score + segment max + rc pack (+ deg hist in CSR mode) ----
__global__ void k_rawmax(const float* __restrict__ s, const float* __restrict__ t,
                         const int* __restrict__ row, const int* __restrict__ col,
                         const float* __restrict__ lb, float* __restrict__ rawex,
                         u32* __restrict__ mxbits, u32* __restrict__ rc,
                         u32* __restrict__ deg, u32 ucap, int E){
  float b = lb[0];
  int i0 = blockIdx.x*blockDim.x + threadIdx.x;
  int nt = gridDim.x*blockDim.x;
  for (int e = i0; e < E; e += nt){
    int r = row[e], c = col[e];
    float raw = (s[r] + t[c]) + b;
    rawex[e] = raw;
    atomicMax(&mxbits[c], f2ord(raw));
    rc[e] = ((u32)r << 16) | (u32)c;        // N < 65536
    if (!ucap){
      atomicAdd(&deg[r], 1u);
      atomicAdd(&deg[c], 1u);
    }
  }
}

// ---------------- ex = exp(raw-mx), den = segsum(ex) in f64 ----------------
// rawex permanently holds ex after this kernel; score is computed on demand
// as ex/den + 0.5 (identical f32 expression everywhere -> identical bits).
__global__ void k_exden(const int* __restrict__ col, const u32* __restrict__ mxbits,
                        float* __restrict__ rawex, double* __restrict__ den, int E){
  int i0 = blockIdx.x*blockDim.x + threadIdx.x;
  int nt = gridDim.x*blockDim.x;
  for (int e = i0; e < E; e += nt){
    int c = col[e];
    float ex = expf(rawex[e] - ord2f(mxbits[c]));
    rawex[e] = ex;
    atomicAdd(&den[c], (double)ex);
  }
}

// ---------------- generic exclusive scan, 3 phases (n <= 65536) ----------------
__global__ void scan_p1(const u32* __restrict__ in, u32* __restrict__ out,
                        u32* __restrict__ bsums, const u32* __restrict__ nptr){
  __shared__ u32 sh[256];
  u32 n = *nptr;
  int t = threadIdx.x;
  u32 i = blockIdx.x*256u + (u32)t;
  u32 v = (i < n) ? in[i] : 0u;
  sh[t] = v; __syncthreads();
  for (int o = 1; o < 256; o <<= 1){
    u32 a = (t >= o) ? sh[t-o] : 0u;
    __syncthreads();
    sh[t] += a;
    __syncthreads();
  }
  if (i < n) out[i] = sh[t] - v;
  if (t == 255) bsums[blockIdx.x] = sh[255];
}
__global__ void scan_p2(u32* bsums, u32* total){
  __shared__ u32 sh[256];
  int t = threadIdx.x;
  u32 v = bsums[t];
  sh[t] = v; __syncthreads();
  for (int o = 1; o < 256; o <<= 1){
    u32 a = (t >= o) ? sh[t-o] : 0u;
    __syncthreads();
    sh[t] += a;
    __syncthreads();
  }
  bsums[t] = sh[t] - v;
  if (t == 255 && total) *total = sh[255];
}
__global__ void scan_p3(u32* out, const u32* __restrict__ bsums, const u32* __restrict__ nptr){
  u32 n = *nptr;
  u32 i = blockIdx.x*256u + threadIdx.x;
  if (i < n) out[i] += bsums[blockIdx.x];
}

// ---------------- adjacency scatter: packed u64, 16 write ranges ----------------
// key = (scorebits-0x3F000000)<<36 | (0xFFFFF-e)<<16 | partner16. Score in
// (0.5,1.5] so sb < 2^24; (score,e) unique -> partner bits never decide a
// comparison. Score computed inline from ex (rawex) and den (L2-resident).
// 16 vertex ranges -> 2.5MB write window per range (< per-XCD L2) so 64B
// lines fill in L2 before writeback; chunk reads stay L2-resident.
__global__ void __launch_bounds__(256)
k_scoreadj(const u32* __restrict__ rc, const float* __restrict__ rawex,
           const double* __restrict__ den, const u32* __restrict__ offarr,
           u32* __restrict__ acur, u64* __restrict__ adj,
           u32 ucap, int ce, int E, int N){
  int rg    = blockIdx.x & 15;
  int chunk = blockIdx.x >> 4;
  int vspan = (N + 15) >> 4;
  int vlo = rg * vspan;
  int vhi = vlo + vspan; if (vhi > N) vhi = N;
  int ebeg = chunk * ce;
  int eend = ebeg + ce; if (eend > E) eend = E;
  for (int e = ebeg + (int)threadIdx.x; e < eend; e += 256){
    u32 pk = rc[e];
    int r = (int)(pk >> 16), c = (int)(pk & 0xFFFFu);
    bool wr = (r >= vlo) & (r < vhi);
    bool wc = (c >= vlo) & (c < vhi);
    if (wr | wc){
      float sc = rawex[e]/(float)den[c] + 0.5f;     // identical expr everywhere
      u32 sb = __float_as_uint(sc) - 0x3F000000u;
      u64 kb = ((u64)sb << 36) | ((u64)(0xFFFFFu - (u32)e) << 16);
      if (wr){
        u32 slot = atomicAdd(&acur[r], 1u);
        if (!ucap || slot < ucap) adj[offarr[r] + slot] = kb | (u32)c;
      }
      if (wc){
        u32 slot = atomicAdd(&acur[c], 1u);
        if (!ucap || slot < ucap) adj[offarr[c] + slot] = kb | (u32)r;
      }
    }
  }
}

// ---------------- per-vertex adjacency sort (descending, pure u64) ----------
__global__ void k_adjsort(const u32* __restrict__ offarr, const u32* __restrict__ acur,
                          u64* __restrict__ adj, u32 ucap, int N){
  __shared__ u64 shk[512];
  int lane = threadIdx.x;    // block = 64 threads (1 wave)
  u32 capn = ucap ? ucap : 0xFFFFFFFFu;
  for (int seg = blockIdx.x; seg < N; seg += gridDim.x){
    u32 base = offarr[seg];
    u32 cnt = acur[seg]; if (cnt > capn) cnt = capn;
    int n = (int)cnt;
    if (n <= 1) continue;
    if (n <= 64){
      u64 v = (lane < n) ? adj[base + lane] : 0ull;
      #pragma unroll
      for (int k2 = 2; k2 <= 64; k2 <<= 1)
        for (int j = k2 >> 1; j > 0; j >>= 1){
          u64 pv = __shfl_xor(v, j);
          bool up  = ((lane & k2) == 0);
          bool low = ((lane & j) == 0);
          u64 mx = v > pv ? v : pv, mn = v > pv ? pv : v;
          v = (up == low) ? mx : mn;     // descending
        }
      if (lane < n) adj[base + lane] = v;
    } else {
      int msz = 128; while (msz < n) msz <<= 1;   // n <= 512
      for (int i = lane; i < msz; i += 64) shk[i] = (i < n) ? adj[base + i] : 0ull;
      __syncthreads();
      for (int k2 = 2; k2 <= msz; k2 <<= 1){
        for (int j = k2 >> 1; j > 0; j >>= 1){
          for (int i = lane; i < msz; i += 64){
            int ix = i ^ j;
            if (ix > i){
              u64 a = shk[i], b2 = shk[ix];
              bool desc = ((i & k2) == 0);
              if (desc ? (a < b2) : (a > b2)){ shk[i] = b2; shk[ix] = a; }
            }
          }
          __syncthreads();
        }
      }
      for (int i = lane; i < n; i += 64) adj[base+i] = shk[i];
      __syncthreads();
    }
  }
}

// ---------------- async suitor matching (== sequential greedy, unique keys) ----
__global__ void k_suitor(const u32* __restrict__ rc, const u32* __restrict__ offarr,
                         const u32* __restrict__ acur, const u64* __restrict__ adj,
                         u64* sw, u32* wpos, u32 ucap, int N){
  int i0 = blockIdx.x*blockDim.x + threadIdx.x;
  int nt = gridDim.x*blockDim.x;
  u32 capn = ucap ? ucap : 0xFFFFFFFFu;
  for (int v0 = i0; v0 < N; v0 += nt){
    u32 u = (u32)v0;
    u32 pos = offarr[u];
    u32 cnt = acur[u]; if (cnt > capn) cnt = capn;
    u32 end = pos + cnt;
    while (pos < end){
      u64 k = adj[pos];
      u32 v = (u32)(k & 0xFFFFu);
      pos++;
      if (sw[v] >= k) continue;                       // monotone-safe pre-check
      stu32(&wpos[u], pos);                           // resume point if displaced
      u64 old = atomicMax((unsigned long long*)&sw[v], (unsigned long long)k);
      if (old >= k) continue;                         // lost the race
      if (old == 0ull) break;                         // accepted, nobody displaced
      // adopt displaced proposer of edge(old): the other endpoint w.r.t. v
      u32 e2 = 0xFFFFFu - (u32)((old >> 16) & 0xFFFFFu);
      u32 p2 = rc[e2];
      u = ((p2 >> 16) == v) ? (p2 & 0xFFFFu) : (p2 >> 16);
      u32 st = offarr[u];
      u32 c2 = acur[u]; if (c2 > capn) c2 = capn;
      end = st + c2;
      u32 wp = ldu32(&wpos[u]);
      pos = (wp > st) ? wp : st;                      // stale -> safe earlier resume
    }
  }
}

// ---------------- extract matching + root flag (fused) ----------------
__global__ void k_exroot(const u64* __restrict__ sw, const u32* __restrict__ rc,
                         int* __restrict__ craw, int* __restrict__ medge,
                         u32* __restrict__ rf, int N){
  int v = blockIdx.x*blockDim.x + threadIdx.x;
  if (v >= N) return;
  u64 k = sw[v];
  bool iscol = false;
  if (k != 0ull){
    u32 e = 0xFFFFFu - (u32)((k >> 16) & 0xFFFFFu);
    u32 p = rc[e]; u32 r = p >> 16, c = p & 0xFFFFu;
    if ((u32)v == c && (sw[r] >> 16) == (k >> 16)){   // same (score,e); partner differs
      craw[c] = (int)r; medge[r] = (int)e;
      iscol = (r != c);                // self-loop: craw[v]=v stays a root
    }
  }
  rf[v] = iscol ? 0u : 1u;
}

// ---------------- cluster ids + zero post-match scratch (fused) ----------------
__global__ void k_clusterzero(const int* __restrict__ craw, const u32* __restrict__ newid,
                              int* __restrict__ clout, float* __restrict__ out, size_t offC,
                              u32* __restrict__ hist, u32* __restrict__ cur2,
                              u32* __restrict__ uniqcnt, int N, int M){
  int i = blockIdx.x*blockDim.x + threadIdx.x;
  if (i < M){ hist[i]=0u; cur2[i]=0u; uniqcnt[i]=0u; }
  if (i < N){
    int cl = (int)newid[craw[i]];
    clout[i] = cl;
    out[offC + i] = (float)cl;
  }
}

__global__ void k_hist(const int* __restrict__ row, const int* __restrict__ clout,
                       u32* __restrict__ hist, int E){
  int i0 = blockIdx.x*blockDim.x + threadIdx.x;
  int nt = gridDim.x*blockDim.x;
  for (int e = i0; e < E; e += nt) atomicAdd(&hist[clout[row[e]]], 1u);
}

// ---------------- ccbuf scatter, range-confined writes (4 passes) ----------------
__global__ void k_scatter(const int* __restrict__ row, const int* __restrict__ col,
                          const int* __restrict__ clout, const u32* __restrict__ segoff,
                          u32* __restrict__ cur2, u32* __restrict__ ccbuf,
                          const u32* __restrict__ hdr, int E){
  const int P = 4;
  int cnum = (int)hdr[2];
  int span = (cnum + P - 1) / P;
  int i0 = blockIdx.x*blockDim.x + threadIdx.x;
  int nt = gridDim.x*blockDim.x;
  for (int p = 0; p < P; p++){
    int lo = p*span;
    int hi = lo + span; if (hi > cnum) hi = cnum;
    for (int e = i0; e < E; e += nt){
      int cr = clout[row[e]];
      if (cr < lo || cr >= hi) continue;
      u32 pos = segoff[cr] + atomicAdd(&cur2[cr], 1u);
      ccbuf[pos] = (u32)clout[col[e]];
    }
  }
}

// ---------------- per-segment sort + dedup (1 wave / block) ----------------
__global__ void k_segsort(const u32* __restrict__ hdr, const u32* __restrict__ hist,
                          const u32* __restrict__ segoff, u32* __restrict__ ccbuf,
                          u32* __restrict__ uniqcnt){
  int c = (int)hdr[2];
  __shared__ u32 sh[1024];
  int lane = threadIdx.x;   // block = 64 threads
  for (int seg = blockIdx.x; seg < c; seg += gridDim.x){
    int n = (int)hist[seg];
    if (n <= 0){ if (lane == 0) uniqcnt[seg] = 0u; continue; }
    u32 off = segoff[seg];
    if (n <= 64){
      u32 v = (lane < n) ? ccbuf[off + lane] : 0xFFFFFFFFu;
      #pragma unroll
      for (int k = 2; k <= 64; k <<= 1)
        for (int j = k >> 1; j > 0; j >>= 1){
          u32 p = __shfl_xor(v, j);
          bool up  = ((lane & k) == 0);
          bool low = ((lane & j) == 0);
          u32 mn = v < p ? v : p, mx = v < p ? p : v;
          v = (up == low) ? mn : mx;
        }
      u32 pv = __shfl_up(v, 1);
      bool un = (lane < n) && (lane == 0 || v != pv);
      u64 bal = __ballot(un);
      int cnt = __popcll(bal);
      int rk  = __popcll(bal & ((1ull << lane) - 1ull));
      if (un) ccbuf[off + rk] = v;
      if (lane == 0) uniqcnt[seg] = (u32)cnt;
    } else {
      int nn = n > 1024 ? 1024 : n;
      for (int i = lane; i < nn; i += 64) sh[i] = ccbuf[off + i];
      __syncthreads();
      for (int p = 0; p < nn; p++){
        int st = p & 1;
        for (int i = lane; 2*i + 1 + st < nn; i += 64){
          int a = 2*i + st;
          u32 x0 = sh[a], x1 = sh[a+1];
          if (x0 > x1){ sh[a] = x1; sh[a+1] = x0; }
        }
        __syncthreads();
      }
      if (lane == 0){
        int cnt = 0; u32 prev = 0u;
        for (int i = 0; i < nn; i++){
          u32 xv = sh[i];
          if (i == 0 || xv != prev){ ccbuf[off + cnt] = xv; cnt++; prev = xv; }
        }
        uniqcnt[seg] = (u32)cnt;
      }
      __syncthreads();
    }
  }
}

// ---------------- write new_edge_index + new_x/new_batch/new_edge_score (fused) ----
__global__ void k_out(const u32* __restrict__ hdr, const u32* __restrict__ segoff,
                      const u32* __restrict__ uniqcnt, const u32* __restrict__ uniqoff,
                      const u32* __restrict__ ccbuf, const int* __restrict__ craw,
                      const u32* __restrict__ newid, const int* __restrict__ medge,
                      const int* __restrict__ row, const int* __restrict__ col,
                      const float* __restrict__ rawex, const double* __restrict__ den,
                      const int* __restrict__ batch, const float* __restrict__ x,
                      float* __restrict__ out, int N){
  int c = (int)hdr[2]; u32 Ep = hdr[3];
  size_t base = (size_t)c * CH_;
  size_t offB = base + 2ull * (size_t)Ep;
  size_t offS = offB + (size_t)c;
  int gw   = (blockIdx.x*blockDim.x + threadIdx.x) >> 6;
  int lane = threadIdx.x & 63;
  int nw   = (gridDim.x*blockDim.x) >> 6;
  // part 1: new_edge_index
  for (int seg = gw; seg < c; seg += nw){
    int cnt = (int)uniqcnt[seg];
    u32 so = segoff[seg], uo = uniqoff[seg];
    for (int j = lane; j < cnt; j += 64){
      u32 cc = ccbuf[so + j];
      out[base + uo + j]              = (float)seg;
      out[base + (size_t)Ep + uo + j] = (float)cc;
    }
  }
  // part 2: new_x / new_batch / new_edge_score (wave per root)
  for (int i = gw; i < N; i += nw){
    if (craw[i] != i) continue;
    int j = (int)newid[i];
    int e = medge[i];
    int lo = i, hi = i; float sc = 1.0f;
    if (e >= 0){
      int r = row[e], cc = col[e];
      lo = min(r, cc); hi = max(r, cc);
      sc = rawex[e]/(float)den[cc] + 0.5f;   // identical expr to k_scoreadj
    }
    float v0 = x[(size_t)lo*CH_ + lane];
    float v1 = x[(size_t)lo*CH_ + 64 + lane];
    if (hi != lo){ v0 += x[(size_t)hi*CH_ + lane]; v1 += x[(size_t)hi*CH_ + 64 + lane]; }
    out[(size_t)j*CH_ + lane]      = v0 * sc;
    out[(size_t)j*CH_ + 64 + lane] = v1 * sc;
    if (lane == 0){
      out[offB + j] = (float)batch[hi];  // CPU-XLA scatter: last (max-index) member wins
      out[offS + j] = sc;
    }
  }
}

extern "C" void kernel_launch(void* const* d_in, const int* in_sizes, int n_in,
                              void* d_out, int out_size, void* d_ws, size_t ws_size,
                              hipStream_t stream) {
  const float* x     = (const float*)d_in[0];
  const int*   eidx  = (const int*)d_in[1];
  const int*   batch = (const int*)d_in[2];
  const float* lw    = (const float*)d_in[3];
  const float* lb    = (const float*)d_in[4];

  int N = in_sizes[0] / CH_;
  int E = in_sizes[1] / 2;
  const int* row = eidx;
  const int* col = eidx + E;
  float* out = (float*)d_out;

  // ---- workspace carve ----
  char* w = (char*)d_ws;
  size_t off = 0;
  auto carve = [&](size_t bytes) -> void* {
    void* p = w + off;
    off += (bytes + 255) & ~(size_t)255;
    return p;
  };
  u32*    hdr    = (u32*)   carve(256);
  double* den    = (double*)carve((size_t)N*8);
  u64*    sw     = (u64*)   carve((size_t)N*8);
  float*  s      = (float*) carve((size_t)N*4);
  float*  t      = (float*) carve((size_t)N*4);
  float*  rawex  = (float*) carve((size_t)E*4);   // raw -> ex (stays ex)
  u32*    mxbits = (u32*)   carve((size_t)N*4);
  int*    craw   = (int*)   carve((size_t)N*4);
  u32*    rf     = (u32*)   carve((size_t)N*4);
  u32*    newid  = (u32*)   carve((size_t)N*4);
  int*    medge  = (int*)   carve((size_t)N*4);
  int*    clout  = (int*)   carve((size_t)N*4);
  u32*    rc     = (u32*)   carve((size_t)E*4);
  u32*    deg    = (u32*)   carve((size_t)N*4);
  u32*    acur   = (u32*)   carve((size_t)N*4);
  u32*    wpos   = (u32*)   carve((size_t)N*4);
  u32*    offarr = (u32*)   carve((size_t)(N+1)*4);
  u32*    bsums  = (u32*)   carve(256*4);

  // bucket mode if workspace allows: cap=80 slots/vertex (P(deg>80) ~ 2e-8,
  // clamped anyway). Falls back to exact CSR (deg+scan) when ws is tight.
  u32 cap = 80;
  size_t adj_b_bytes = ((size_t)N*cap*8 + 255) & ~(size_t)255;
  bool buckets = (off + adj_b_bytes + (1u<<20) <= ws_size);
  u64* adj;
  if (buckets){
    adj = (u64*)carve((size_t)N*cap*8);
  } else {
    cap = 0;
    adj = (u64*)carve((size_t)(2*(size_t)E)*8);
  }
  // alias post-match scratch into the (then-dead) adj region
  char* a = (char*)adj;
  size_t aoff = 0;
  auto acarve = [&](size_t bytes) -> void* {
    void* p = a + aoff;
    aoff += (bytes + 255) & ~(size_t)255;
    return p;
  };
  u32* ccbuf   = (u32*)acarve((size_t)E*4);
  u32* hist    = (u32*)acarve((size_t)(N+64)*4);
  u32* segoff  = (u32*)acarve((size_t)(N+64)*4);
  u32* cur2    = (u32*)acarve((size_t)(N+64)*4);
  u32* uniqcnt = (u32*)acarve((size_t)(N+64)*4);
  u32* uniqoff = (u32*)acarve((size_t)(N+64)*4);
  (void)n_in;

  int nbE = (E + 255) / 256;
  int nbN = (N + 255) / 256;
  int ce  = 4096;                        // edges per scoreadj chunk
  int kch = (E + ce - 1) / ce;           // chunks -> grid = 16*kch

  k_init<<<512, 256, 0, stream>>>(hdr, mxbits, den, sw, craw, medge, deg, acur,
                                  wpos, offarr, cap, N, E);
  k_dots<<<(N + 3)/4, 256, 0, stream>>>(x, lw, s, t, N);
  k_rawmax<<<nbE, 256, 0, stream>>>(s, t, row, col, lb, rawex, mxbits, rc, deg, cap, E);
  k_exden<<<nbE, 256, 0, stream>>>(col, mxbits, rawex, den, E);

  if (!buckets){
    // scan deg -> offarr (exclusive); n from hdr[6] (= N)
    scan_p1<<<256, 256, 0, stream>>>(deg, offarr, bsums, &hdr[6]);
    scan_p2<<<1, 256, 0, stream>>>(bsums, &hdr[7]);
    scan_p3<<<256, 256, 0, stream>>>(offarr, bsums, &hdr[6]);
  }

  k_scoreadj<<<16*kch, 256, 0, stream>>>(rc, rawex, den, offarr, acur, adj, cap, ce, E, N);
  k_adjsort<<<4096, 64, 0, stream>>>(offarr, acur, adj, cap, N);
  k_suitor<<<nbN, 256, 0, stream>>>(rc, offarr, acur, adj, sw, wpos, cap, N);
  k_exroot<<<nbN, 256, 0, stream>>>(sw, rc, craw, medge, rf, N);

  // scan rf -> newid ; total -> hdr[2] (= c)
  scan_p1<<<256, 256, 0, stream>>>(rf, newid, bsums, &hdr[6]);
  scan_p2<<<1, 256, 0, stream>>>(bsums, &hdr[2]);
  scan_p3<<<256, 256, 0, stream>>>(newid, bsums, &hdr[6]);

  k_clusterzero<<<(N + 64 + 255)/256, 256, 0, stream>>>(craw, newid, clout, out,
                                                        (size_t)(out_size - N),
                                                        hist, cur2, uniqcnt, N, N + 64);
  k_hist<<<nbE, 256, 0, stream>>>(row, clout, hist, E);

  // scan hist -> segoff ; n from hdr[2] (= c)
  scan_p1<<<256, 256, 0, stream>>>(hist, segoff, bsums, &hdr[2]);
  scan_p2<<<1, 256, 0, stream>>>(bsums, &hdr[4]);
  scan_p3<<<256, 256, 0, stream>>>(segoff, bsums, &hdr[2]);

  k_scatter<<<nbE, 256, 0, stream>>>(row, col, clout, segoff, cur2, ccbuf, hdr, E);
  k_segsort<<<4096, 64, 0, stream>>>(hdr, hist, segoff, ccbuf, uniqcnt);

  // scan uniqcnt -> uniqoff ; total -> hdr[3] (= E')
  scan_p1<<<256, 256, 0, stream>>>(uniqcnt, uniqoff, bsums, &hdr[2]);
  scan_p2<<<1, 256, 0, stream>>>(bsums, &hdr[3]);
  scan_p3<<<256, 256, 0, stream>>>(uniqoff, bsums, &hdr[2]);

  k_out<<<4096, 256, 0, stream>>>(hdr, segoff, uniqcnt, uniqoff, ccbuf, craw, newid,
                                  medge, row, col, rawex, den, batch, x, out, N);
}

// Round 20
// 430.347 us; speedup vs baseline: 1.0160x; 1.0160x over previous
//
#include <hip/hip_runtime.h>

typedef unsigned int u32;
typedef unsigned short u16;
typedef unsigned long long u64;

#define CH_ 128

__device__ __forceinline__ u32 f2ord(float f){
  u32 u = __float_as_uint(f);
  return ((int)u < 0) ? ~u : (u | 0x80000000u);
}
__device__ __forceinline__ float ord2f(u32 u){
  return (u & 0x80000000u) ? __uint_as_float(u & 0x7FFFFFFFu) : __uint_as_float(~u);
}
__device__ __forceinline__ u32 ldu32(const u32* p){
  return __hip_atomic_load(p, __ATOMIC_RELAXED, __HIP_MEMORY_SCOPE_AGENT);
}
__device__ __forceinline__ void stu32(u32* p, u32 v){
  __hip_atomic_store(p, v, __ATOMIC_RELAXED, __HIP_MEMORY_SCOPE_AGENT);
}

// ---------------- init ----------------
// ucap > 0: bucket mode -> offarr[v] = v*ucap (no deg scan needed)
__global__ void k_init(u32* hdr, u32* mxbits, double* den, u64* sw,
                       int* craw, int* medge, u32* deg, u32* acur,
                       u32* wpos, u32* offarr, u32 ucap, int N, int E){
  int i0 = blockIdx.x*blockDim.x + threadIdx.x;
  int nt = gridDim.x*blockDim.x;
  for (int v = i0; v < N; v += nt){
    mxbits[v]=0u; den[v]=0.0; sw[v]=0ull; craw[v]=v; medge[v]=-1;
    deg[v]=0u; acur[v]=0u; wpos[v]=0u;
    if (ucap) offarr[v] = (u32)v * ucap;
  }
  if (i0 == 0){
    for (int i = 0; i < 64; i++) hdr[i] = 0u;
    hdr[6] = (u32)N;
    offarr[N] = ucap ? (u32)N*ucap : (u32)(2*E);
  }
}

// ---------------- per-node dot products: s=x.w1, t=x.w2 ----------------
__global__ void k_dots(const float* __restrict__ x, const float* __restrict__ lw,
                       float* __restrict__ s, float* __restrict__ t, int N){
  int wid = threadIdx.x >> 6, lane = threadIdx.x & 63;
  int node = blockIdx.x*4 + wid;
  if (node >= N) return;
  const float* xr = x + (size_t)node*CH_;
  float xa = xr[lane], xb = xr[64+lane];
  float sv = xa*lw[lane]      + xb*lw[64+lane];
  float tv = xa*lw[128+lane]  + xb*lw[192+lane];
  #pragma unroll
  for (int m = 1; m < 64; m <<= 1){ sv += __shfl_xor(sv, m); tv += __shfl_xor(tv, m); }
  if (lane == 0){ s[node]=sv; t[node]=tv; }
}

// ---------------- raw score + segment max + rc pack (+ deg hist in CSR mode) ----
__global__ void k_rawmax(const float* __restrict__ s, const float* __restrict__ t,
                         const int* __restrict__ row, const int* __restrict__ col,
                         const float* __restrict__ lb, float* __restrict__ rawex,
                         u32* __restrict__ mxbits, u32* __restrict__ rc,
                         u32* __restrict__ deg, u32 ucap, int E){
  float b = lb[0];
  int i0 = blockIdx.x*blockDim.x + threadIdx.x;
  int nt = gridDim.x*blockDim.x;
  for (int e = i0; e < E; e += nt){
    int r = row[e], c = col[e];
    float raw = (s[r] + t[c]) + b;
    rawex[e] = raw;
    atomicMax(&mxbits[c], f2ord(raw));
    rc[e] = ((u32)r << 16) | (u32)c;        // N < 65536
    if (!ucap){
      atomicAdd(&deg[r], 1u);
      atomicAdd(&deg[c], 1u);
    }
  }
}

// ---------------- ex = exp(raw-mx), den = segsum(ex) in f64 ----------------
// rawex permanently holds ex after this kernel; score is computed on demand
// as ex/den + 0.5 (identical f32 expression everywhere -> identical bits).
__global__ void k_exden(const int* __restrict__ col, const u32* __restrict__ mxbits,
                        float* __restrict__ rawex, double* __restrict__ den, int E){
  int i0 = blockIdx.x*blockDim.x + threadIdx.x;
  int nt = gridDim.x*blockDim.x;
  for (int e = i0; e < E; e += nt){
    int c = col[e];
    float ex = expf(rawex[e] - ord2f(mxbits[c]));
    rawex[e] = ex;
    atomicAdd(&den[c], (double)ex);
  }
}

// ---------------- generic exclusive scan, 3 phases (n <= 65536) ----------------
__global__ void scan_p1(const u32* __restrict__ in, u32* __restrict__ out,
                        u32* __restrict__ bsums, const u32* __restrict__ nptr){
  __shared__ u32 sh[256];
  u32 n = *nptr;
  int t = threadIdx.x;
  u32 i = blockIdx.x*256u + (u32)t;
  u32 v = (i < n) ? in[i] : 0u;
  sh[t] = v; __syncthreads();
  for (int o = 1; o < 256; o <<= 1){
    u32 a = (t >= o) ? sh[t-o] : 0u;
    __syncthreads();
    sh[t] += a;
    __syncthreads();
  }
  if (i < n) out[i] = sh[t] - v;
  if (t == 255) bsums[blockIdx.x] = sh[255];
}
__global__ void scan_p2(u32* bsums, u32* total){
  __shared__ u32 sh[256];
  int t = threadIdx.x;
  u32 v = bsums[t];
  sh[t] = v; __syncthreads();
  for (int o = 1; o < 256; o <<= 1){
    u32 a = (t >= o) ? sh[t-o] : 0u;
    __syncthreads();
    sh[t] += a;
    __syncthreads();
  }
  bsums[t] = sh[t] - v;
  if (t == 255 && total) *total = sh[255];
}
__global__ void scan_p3(u32* out, const u32* __restrict__ bsums, const u32* __restrict__ nptr){
  u32 n = *nptr;
  u32 i = blockIdx.x*256u + threadIdx.x;
  if (i < n) out[i] += bsums[blockIdx.x];
}

// ---------------- adjacency scatter: packed u64, 8 write ranges ----------------
// key = (scorebits-0x3F000000)<<36 | (0xFFFFF-e)<<16 | partner16. Score in
// (0.5,1.5] so sb < 2^24; (score,e) unique -> partner bits never decide a
// comparison. Score computed inline from ex (rawex) and den (L2-resident).
// P=8 measured optimum (P=16 doubled redundant reads for no WRITE gain).
__global__ void __launch_bounds__(256)
k_scoreadj(const u32* __restrict__ rc, const float* __restrict__ rawex,
           const double* __restrict__ den, const u32* __restrict__ offarr,
           u32* __restrict__ acur, u64* __restrict__ adj,
           u32 ucap, int ce, int E, int N){
  int rg    = blockIdx.x & 7;
  int chunk = blockIdx.x >> 3;
  int vspan = (N + 7) >> 3;
  int vlo = rg * vspan;
  int vhi = vlo + vspan; if (vhi > N) vhi = N;
  int ebeg = chunk * ce;
  int eend = ebeg + ce; if (eend > E) eend = E;
  for (int e = ebeg + (int)threadIdx.x; e < eend; e += 256){
    u32 pk = rc[e];
    int r = (int)(pk >> 16), c = (int)(pk & 0xFFFFu);
    bool wr = (r >= vlo) & (r < vhi);
    bool wc = (c >= vlo) & (c < vhi);
    if (wr | wc){
      float sc = rawex[e]/(float)den[c] + 0.5f;     // identical expr everywhere
      u32 sb = __float_as_uint(sc) - 0x3F000000u;
      u64 kb = ((u64)sb << 36) | ((u64)(0xFFFFFu - (u32)e) << 16);
      if (wr){
        u32 slot = atomicAdd(&acur[r], 1u);
        if (!ucap || slot < ucap) adj[offarr[r] + slot] = kb | (u32)c;
      }
      if (wc){
        u32 slot = atomicAdd(&acur[c], 1u);
        if (!ucap || slot < ucap) adj[offarr[c] + slot] = kb | (u32)r;
      }
    }
  }
}

// ---------------- per-vertex adjacency sort (descending, pure u64) ----------
__global__ void k_adjsort(const u32* __restrict__ offarr, const u32* __restrict__ acur,
                          u64* __restrict__ adj, u32 ucap, int N){
  __shared__ u64 shk[512];
  int lane = threadIdx.x;    // block = 64 threads (1 wave)
  u32 capn = ucap ? ucap : 0xFFFFFFFFu;
  for (int seg = blockIdx.x; seg < N; seg += gridDim.x){
    u32 base = offarr[seg];
    u32 cnt = acur[seg]; if (cnt > capn) cnt = capn;
    int n = (int)cnt;
    if (n <= 1) continue;
    if (n <= 64){
      u64 v = (lane < n) ? adj[base + lane] : 0ull;
      #pragma unroll
      for (int k2 = 2; k2 <= 64; k2 <<= 1)
        for (int j = k2 >> 1; j > 0; j >>= 1){
          u64 pv = __shfl_xor(v, j);
          bool up  = ((lane & k2) == 0);
          bool low = ((lane & j) == 0);
          u64 mx = v > pv ? v : pv, mn = v > pv ? pv : v;
          v = (up == low) ? mx : mn;     // descending
        }
      if (lane < n) adj[base + lane] = v;
    } else {
      int msz = 128; while (msz < n) msz <<= 1;   // n <= 512
      for (int i = lane; i < msz; i += 64) shk[i] = (i < n) ? adj[base + i] : 0ull;
      __syncthreads();
      for (int k2 = 2; k2 <= msz; k2 <<= 1){
        for (int j = k2 >> 1; j > 0; j >>= 1){
          for (int i = lane; i < msz; i += 64){
            int ix = i ^ j;
            if (ix > i){
              u64 a = shk[i], b2 = shk[ix];
              bool desc = ((i & k2) == 0);
              if (desc ? (a < b2) : (a > b2)){ shk[i] = b2; shk[ix] = a; }
            }
          }
          __syncthreads();
        }
      }
      for (int i = lane; i < n; i += 64) adj[base+i] = shk[i];
      __syncthreads();
    }
  }
}

// ---------------- async suitor matching (== sequential greedy, unique keys) ----
__global__ void k_suitor(const u32* __restrict__ rc, const u32* __restrict__ offarr,
                         const u32* __restrict__ acur, const u64* __restrict__ adj,
                         u64* sw, u32* wpos, u32 ucap, int N){
  int i0 = blockIdx.x*blockDim.x + threadIdx.x;
  int nt = gridDim.x*blockDim.x;
  u32 capn = ucap ? ucap : 0xFFFFFFFFu;
  for (int v0 = i0; v0 < N; v0 += nt){
    u32 u = (u32)v0;
    u32 pos = offarr[u];
    u32 cnt = acur[u]; if (cnt > capn) cnt = capn;
    u32 end = pos + cnt;
    while (pos < end){
      u64 k = adj[pos];
      u32 v = (u32)(k & 0xFFFFu);
      pos++;
      if (sw[v] >= k) continue;                       // monotone-safe pre-check
      stu32(&wpos[u], pos);                           // resume point if displaced
      u64 old = atomicMax((unsigned long long*)&sw[v], (unsigned long long)k);
      if (old >= k) continue;                         // lost the race
      if (old == 0ull) break;                         // accepted, nobody displaced
      // adopt displaced proposer of edge(old): the other endpoint w.r.t. v
      u32 e2 = 0xFFFFFu - (u32)((old >> 16) & 0xFFFFFu);
      u32 p2 = rc[e2];
      u = ((p2 >> 16) == v) ? (p2 & 0xFFFFu) : (p2 >> 16);
      u32 st = offarr[u];
      u32 c2 = acur[u]; if (c2 > capn) c2 = capn;
      end = st + c2;
      u32 wp = ldu32(&wpos[u]);
      pos = (wp > st) ? wp : st;                      // stale -> safe earlier resume
    }
  }
}

// ---------------- extract matching + root flag (fused) ----------------
__global__ void k_exroot(const u64* __restrict__ sw, const u32* __restrict__ rc,
                         int* __restrict__ craw, int* __restrict__ medge,
                         u32* __restrict__ rf, int N){
  int v = blockIdx.x*blockDim.x + threadIdx.x;
  if (v >= N) return;
  u64 k = sw[v];
  bool iscol = false;
  if (k != 0ull){
    u32 e = 0xFFFFFu - (u32)((k >> 16) & 0xFFFFFu);
    u32 p = rc[e]; u32 r = p >> 16, c = p & 0xFFFFu;
    if ((u32)v == c && (sw[r] >> 16) == (k >> 16)){   // same (score,e); partner differs
      craw[c] = (int)r; medge[r] = (int)e;
      iscol = (r != c);                // self-loop: craw[v]=v stays a root
    }
  }
  rf[v] = iscol ? 0u : 1u;
}

// ---------------- cluster ids + zero post-match scratch (fused) ----------------
__global__ void k_clusterzero(const int* __restrict__ craw, const u32* __restrict__ newid,
                              int* __restrict__ clout, float* __restrict__ out, size_t offC,
                              u32* __restrict__ hist, u32* __restrict__ cur2,
                              u32* __restrict__ uniqcnt, int N, int M){
  int i = blockIdx.x*blockDim.x + threadIdx.x;
  if (i < M){ hist[i]=0u; cur2[i]=0u; uniqcnt[i]=0u; }
  if (i < N){
    int cl = (int)newid[craw[i]];
    clout[i] = cl;
    out[offC + i] = (float)cl;
  }
}

__global__ void k_hist(const int* __restrict__ row, const int* __restrict__ clout,
                       u32* __restrict__ hist, int E){
  int i0 = blockIdx.x*blockDim.x + threadIdx.x;
  int nt = gridDim.x*blockDim.x;
  for (int e = i0; e < E; e += nt) atomicAdd(&hist[clout[row[e]]], 1u);
}

// ---------------- ccbuf scatter, range-confined writes (4 passes) ----------------
__global__ void k_scatter(const int* __restrict__ row, const int* __restrict__ col,
                          const int* __restrict__ clout, const u32* __restrict__ segoff,
                          u32* __restrict__ cur2, u32* __restrict__ ccbuf,
                          const u32* __restrict__ hdr, int E){
  const int P = 4;
  int cnum = (int)hdr[2];
  int span = (cnum + P - 1) / P;
  int i0 = blockIdx.x*blockDim.x + threadIdx.x;
  int nt = gridDim.x*blockDim.x;
  for (int p = 0; p < P; p++){
    int lo = p*span;
    int hi = lo + span; if (hi > cnum) hi = cnum;
    for (int e = i0; e < E; e += nt){
      int cr = clout[row[e]];
      if (cr < lo || cr >= hi) continue;
      u32 pos = segoff[cr] + atomicAdd(&cur2[cr], 1u);
      ccbuf[pos] = (u32)clout[col[e]];
    }
  }
}

// ---------------- per-segment sort + dedup (1 wave / block) ----------------
__global__ void k_segsort(const u32* __restrict__ hdr, const u32* __restrict__ hist,
                          const u32* __restrict__ segoff, u32* __restrict__ ccbuf,
                          u32* __restrict__ uniqcnt){
  int c = (int)hdr[2];
  __shared__ u32 sh[1024];
  int lane = threadIdx.x;   // block = 64 threads
  for (int seg = blockIdx.x; seg < c; seg += gridDim.x){
    int n = (int)hist[seg];
    if (n <= 0){ if (lane == 0) uniqcnt[seg] = 0u; continue; }
    u32 off = segoff[seg];
    if (n <= 64){
      u32 v = (lane < n) ? ccbuf[off + lane] : 0xFFFFFFFFu;
      #pragma unroll
      for (int k = 2; k <= 64; k <<= 1)
        for (int j = k >> 1; j > 0; j >>= 1){
          u32 p = __shfl_xor(v, j);
          bool up  = ((lane & k) == 0);
          bool low = ((lane & j) == 0);
          u32 mn = v < p ? v : p, mx = v < p ? p : v;
          v = (up == low) ? mn : mx;
        }
      u32 pv = __shfl_up(v, 1);
      bool un = (lane < n) && (lane == 0 || v != pv);
      u64 bal = __ballot(un);
      int cnt = __popcll(bal);
      int rk  = __popcll(bal & ((1ull << lane) - 1ull));
      if (un) ccbuf[off + rk] = v;
      if (lane == 0) uniqcnt[seg] = (u32)cnt;
    } else {
      int nn = n > 1024 ? 1024 : n;
      for (int i = lane; i < nn; i += 64) sh[i] = ccbuf[off + i];
      __syncthreads();
      for (int p = 0; p < nn; p++){
        int st = p & 1;
        for (int i = lane; 2*i + 1 + st < nn; i += 64){
          int a = 2*i + st;
          u32 x0 = sh[a], x1 = sh[a+1];
          if (x0 > x1){ sh[a] = x1; sh[a+1] = x0; }
        }
        __syncthreads();
      }
      if (lane == 0){
        int cnt = 0; u32 prev = 0u;
        for (int i = 0; i < nn; i++){
          u32 xv = sh[i];
          if (i == 0 || xv != prev){ ccbuf[off + cnt] = xv; cnt++; prev = xv; }
        }
        uniqcnt[seg] = (u32)cnt;
      }
      __syncthreads();
    }
  }
}

// ---------------- write new_edge_index + new_x/new_batch/new_edge_score (fused) ----
__global__ void k_out(const u32* __restrict__ hdr, const u32* __restrict__ segoff,
                      const u32* __restrict__ uniqcnt, const u32* __restrict__ uniqoff,
                      const u32* __restrict__ ccbuf, const int* __restrict__ craw,
                      const u32* __restrict__ newid, const int* __restrict__ medge,
                      const int* __restrict__ row, const int* __restrict__ col,
                      const float* __restrict__ rawex, const double* __restrict__ den,
                      const int* __restrict__ batch, const float* __restrict__ x,
                      float* __restrict__ out, int N){
  int c = (int)hdr[2]; u32 Ep = hdr[3];
  size_t base = (size_t)c * CH_;
  size_t offB = base + 2ull * (size_t)Ep;
  size_t offS = offB + (size_t)c;
  int gw   = (blockIdx.x*blockDim.x + threadIdx.x) >> 6;
  int lane = threadIdx.x & 63;
  int nw   = (gridDim.x*blockDim.x) >> 6;
  // part 1: new_edge_index
  for (int seg = gw; seg < c; seg += nw){
    int cnt = (int)uniqcnt[seg];
    u32 so = segoff[seg], uo = uniqoff[seg];
    for (int j = lane; j < cnt; j += 64){
      u32 cc = ccbuf[so + j];
      out[base + uo + j]              = (float)seg;
      out[base + (size_t)Ep + uo + j] = (float)cc;
    }
  }
  // part 2: new_x / new_batch / new_edge_score (wave per root)
  for (int i = gw; i < N; i += nw){
    if (craw[i] != i) continue;
    int j = (int)newid[i];
    int e = medge[i];
    int lo = i, hi = i; float sc = 1.0f;
    if (e >= 0){
      int r = row[e], cc = col[e];
      lo = min(r, cc); hi = max(r, cc);
      sc = rawex[e]/(float)den[cc] + 0.5f;   // identical expr to k_scoreadj
    }
    float v0 = x[(size_t)lo*CH_ + lane];
    float v1 = x[(size_t)lo*CH_ + 64 + lane];
    if (hi != lo){ v0 += x[(size_t)hi*CH_ + lane]; v1 += x[(size_t)hi*CH_ + 64 + lane]; }
    out[(size_t)j*CH_ + lane]      = v0 * sc;
    out[(size_t)j*CH_ + 64 + lane] = v1 * sc;
    if (lane == 0){
      out[offB + j] = (float)batch[hi];  // CPU-XLA scatter: last (max-index) member wins
      out[offS + j] = sc;
    }
  }
}

extern "C" void kernel_launch(void* const* d_in, const int* in_sizes, int n_in,
                              void* d_out, int out_size, void* d_ws, size_t ws_size,
                              hipStream_t stream) {
  const float* x     = (const float*)d_in[0];
  const int*   eidx  = (const int*)d_in[1];
  const int*   batch = (const int*)d_in[2];
  const float* lw    = (const float*)d_in[3];
  const float* lb    = (const float*)d_in[4];

  int N = in_sizes[0] / CH_;
  int E = in_sizes[1] / 2;
  const int* row = eidx;
  const int* col = eidx + E;
  float* out = (float*)d_out;

  // ---- workspace carve ----
  char* w = (char*)d_ws;
  size_t off = 0;
  auto carve = [&](size_t bytes) -> void* {
    void* p = w + off;
    off += (bytes + 255) & ~(size_t)255;
    return p;
  };
  u32*    hdr    = (u32*)   carve(256);
  double* den    = (double*)carve((size_t)N*8);
  u64*    sw     = (u64*)   carve((size_t)N*8);
  float*  s      = (float*) carve((size_t)N*4);
  float*  t      = (float*) carve((size_t)N*4);
  float*  rawex  = (float*) carve((size_t)E*4);   // raw -> ex (stays ex)
  u32*    mxbits = (u32*)   carve((size_t)N*4);
  int*    craw   = (int*)   carve((size_t)N*4);
  u32*    rf     = (u32*)   carve((size_t)N*4);
  u32*    newid  = (u32*)   carve((size_t)N*4);
  int*    medge  = (int*)   carve((size_t)N*4);
  int*    clout  = (int*)   carve((size_t)N*4);
  u32*    rc     = (u32*)   carve((size_t)E*4);
  u32*    deg    = (u32*)   carve((size_t)N*4);
  u32*    acur   = (u32*)   carve((size_t)N*4);
  u32*    wpos   = (u32*)   carve((size_t)N*4);
  u32*    offarr = (u32*)   carve((size_t)(N+1)*4);
  u32*    bsums  = (u32*)   carve(256*4);

  // bucket mode if workspace allows: cap=80 slots/vertex (P(deg>80) ~ 2e-8,
  // clamped anyway). Falls back to exact CSR (deg+scan) when ws is tight.
  u32 cap = 80;
  size_t adj_b_bytes = ((size_t)N*cap*8 + 255) & ~(size_t)255;
  bool buckets = (off + adj_b_bytes + (1u<<20) <= ws_size);
  u64* adj;
  if (buckets){
    adj = (u64*)carve((size_t)N*cap*8);
  } else {
    cap = 0;
    adj = (u64*)carve((size_t)(2*(size_t)E)*8);
  }
  // alias post-match scratch into the (then-dead) adj region
  char* a = (char*)adj;
  size_t aoff = 0;
  auto acarve = [&](size_t bytes) -> void* {
    void* p = a + aoff;
    aoff += (bytes + 255) & ~(size_t)255;
    return p;
  };
  u32* ccbuf   = (u32*)acarve((size_t)E*4);
  u32* hist    = (u32*)acarve((size_t)(N+64)*4);
  u32* segoff  = (u32*)acarve((size_t)(N+64)*4);
  u32* cur2    = (u32*)acarve((size_t)(N+64)*4);
  u32* uniqcnt = (u32*)acarve((size_t)(N+64)*4);
  u32* uniqoff = (u32*)acarve((size_t)(N+64)*4);
  (void)n_in;

  int nbE = (E + 255) / 256;
  int nbN = (N + 255) / 256;
  int ce  = 4096;                        // edges per scoreadj chunk
  int kch = (E + ce - 1) / ce;           // chunks -> grid = 8*kch

  k_init<<<512, 256, 0, stream>>>(hdr, mxbits, den, sw, craw, medge, deg, acur,
                                  wpos, offarr, cap, N, E);
  k_dots<<<(N + 3)/4, 256, 0, stream>>>(x, lw, s, t, N);
  k_rawmax<<<nbE, 256, 0, stream>>>(s, t, row, col, lb, rawex, mxbits, rc, deg, cap, E);
  k_exden<<<nbE, 256, 0, stream>>>(col, mxbits, rawex, den, E);

  if (!buckets){
    // scan deg -> offarr (exclusive); n from hdr[6] (= N)
    scan_p1<<<256, 256, 0, stream>>>(deg, offarr, bsums, &hdr[6]);
    scan_p2<<<1, 256, 0, stream>>>(bsums, &hdr[7]);
    scan_p3<<<256, 256, 0, stream>>>(offarr, bsums, &hdr[6]);
  }

  k_scoreadj<<<8*kch, 256, 0, stream>>>(rc, rawex, den, offarr, acur, adj, cap, ce, E, N);
  k_adjsort<<<4096, 64, 0, stream>>>(offarr, acur, adj, cap, N);
  k_suitor<<<nbN, 256, 0, stream>>>(rc, offarr, acur, adj, sw, wpos, cap, N);
  k_exroot<<<nbN, 256, 0, stream>>>(sw, rc, craw, medge, rf, N);

  // scan rf -> newid ; total -> hdr[2] (= c)
  scan_p1<<<256, 256, 0, stream>>>(rf, newid, bsums, &hdr[6]);
  scan_p2<<<1, 256, 0, stream>>>(bsums, &hdr[2]);
  scan_p3<<<256, 256, 0, stream>>>(newid, bsums, &hdr[6]);

  k_clusterzero<<<(N + 64 + 255)/256, 256, 0, stream>>>(craw, newid, clout, out,
                                                        (size_t)(out_size - N),
                                                        hist, cur2, uniqcnt, N, N + 64);
  k_hist<<<nbE, 256, 0, stream>>>(row, clout, hist, E);

  // scan hist -> segoff ; n from hdr[2] (= c)
  scan_p1<<<256, 256, 0, stream>>>(hist, segoff, bsums, &hdr[2]);
  scan_p2<<<1, 256, 0, stream>>>(bsums, &hdr[4]);
  scan_p3<<<256, 256, 0, stream>>>(segoff, bsums, &hdr[2]);

  k_scatter<<<nbE, 256, 0, stream>>>(row, col, clout, segoff, cur2, ccbuf, hdr, E);
  k_segsort<<<4096, 64, 0, stream>>>(hdr, hist, segoff, ccbuf, uniqcnt);

  // scan uniqcnt -> uniqoff ; total -> hdr[3] (= E')
  scan_p1<<<256, 256, 0, stream>>>(uniqcnt, uniqoff, bsums, &hdr[2]);
  scan_p2<<<1, 256, 0, stream>>>(bsums, &hdr[3]);
  scan_p3<<<256, 256, 0, stream>>>(uniqoff, bsums, &hdr[2]);

  k_out<<<4096, 256, 0, stream>>>(hdr, segoff, uniqcnt, uniqoff, ccbuf, craw, newid,
                                  medge, row, col, rawex, den, batch, x, out, N);
}